// Round 2
// baseline (668.137 us; speedup 1.0000x reference)
//
#include <hip/hip_runtime.h>

// Problem constants: B=8, T=256, U=64, D=640, V=1024
//   enc  [8,256,640] f32, pred [8,64,640] f32, W [1024,1280] f32, bias [1024] f32
//   out  = [131072,1024] f32 joint ++ [8] source_lengths ++ [8] target_lengths
//
// Factorization: relu(concat(e,p)) @ W^T = relu(e)@W[:, :640]^T + relu(p)@W[:, 640:]^T
//   P[bu, v] = sum_d relu(pred[bu,d]) * W[v,640+d]              (512 x 1024, kernel 1)
//   out[bt*64+u, v] = (E[bt,v]+bias[v]) + P[(bt>>8)*64+u, v]    (fused kernel 2: E never hits HBM)

typedef float floatx4 __attribute__((ext_vector_type(4)));  // native vector for nt-store

// ---------------- Kernel 1: P = relu(pred) @ W2^T (no bias) ----------------
#define PBM 64
#define PBN 64
#define PBK 16
#define PPAD 4

__global__ __launch_bounds__(256) void p_gemm_kernel(
    const float* __restrict__ pred,  // [512, 640]
    const float* __restrict__ W,     // [1024, 1280]
    float* __restrict__ P)           // [512, 1024]
{
    __shared__ float As[PBK][PBM + PPAD];
    __shared__ float Bs[PBK][PBN + PPAD];

    const int tid  = threadIdx.x;
    const int row0 = blockIdx.y * PBM;   // 0..448
    const int col0 = blockIdx.x * PBN;   // 0..960

    const int lm = tid >> 2;          // 0..63
    const int lk = (tid & 3) * 4;     // 0,4,8,12
    const int tx = tid & 15;
    const int ty = tid >> 4;

    float acc[4][4];
    #pragma unroll
    for (int i = 0; i < 4; ++i)
        #pragma unroll
        for (int j = 0; j < 4; ++j) acc[i][j] = 0.f;

    for (int k0 = 0; k0 < 640; k0 += PBK) {
        float4 a4 = *(const float4*)(pred + (size_t)(row0 + lm) * 640 + k0 + lk);
        float4 b4 = *(const float4*)(W + (size_t)(col0 + lm) * 1280 + 640 + k0 + lk);
        As[lk + 0][lm] = fmaxf(a4.x, 0.f);
        As[lk + 1][lm] = fmaxf(a4.y, 0.f);
        As[lk + 2][lm] = fmaxf(a4.z, 0.f);
        As[lk + 3][lm] = fmaxf(a4.w, 0.f);
        Bs[lk + 0][lm] = b4.x;
        Bs[lk + 1][lm] = b4.y;
        Bs[lk + 2][lm] = b4.z;
        Bs[lk + 3][lm] = b4.w;
        __syncthreads();

        #pragma unroll
        for (int k = 0; k < PBK; ++k) {
            float4 av = *(const float4*)&As[k][ty * 4];
            float4 bv = *(const float4*)&Bs[k][tx * 4];
            float ar[4] = {av.x, av.y, av.z, av.w};
            float br[4] = {bv.x, bv.y, bv.z, bv.w};
            #pragma unroll
            for (int i = 0; i < 4; ++i)
                #pragma unroll
                for (int j = 0; j < 4; ++j)
                    acc[i][j] = fmaf(ar[i], br[j], acc[i][j]);
        }
        __syncthreads();
    }

    #pragma unroll
    for (int i = 0; i < 4; ++i) {
        float4 o;
        o.x = acc[i][0]; o.y = acc[i][1]; o.z = acc[i][2]; o.w = acc[i][3];
        *(float4*)(P + (size_t)(row0 + ty * 4 + i) * 1024 + col0 + tx * 4) = o;
    }
}

// ---------------- Kernel 2: fused E-GEMM + broadcast-add + write ----------------
// Block tile: 16 bt-rows x 256 v-cols. 128 threads = 2 waves.
//   wave w (= t>>6) owns rows bt0 + w*8 .. +7 ; lane l (= t&63) owns cols v0 + l*4 .. +3
//   micro-tile 8t x 4v per thread, acc[8][4].
// Phase A: E-tile GEMM over K=640 (BK=16). A-reads are wave-uniform broadcasts (cheap);
//          B-reads are contiguous 1 KB ds_read_b128 -> ~1.5 B LDS per FMA vs 2.0 before.
// Phase B: for each u: read P row-segment (1 KB, L2-resident) to regs, emit 8 nt-stores.

#define TT 16
#define VT 256
#define KB 16

__global__ __launch_bounds__(128) void e_fused_kernel(
    const float* __restrict__ enc,   // [2048, 640]
    const float* __restrict__ W,     // [1024, 1280]
    const float* __restrict__ bias,  // [1024]
    const float* __restrict__ P,     // [512, 1024]
    float* __restrict__ out)         // [131072, 1024]
{
    __shared__ float As[KB][TT];     // 16 x 16  (1 KB)
    __shared__ float Ws[KB][VT];     // 16 x 256 (16 KB)

    const int t   = threadIdx.x;     // 0..127
    const int vt  = blockIdx.x;      // 0..3
    const int tt  = blockIdx.y;      // 0..127
    const int bt0 = tt * TT;         // tile rows bt0..bt0+15, all in batch b
    const int v0  = vt * VT;
    const int b   = bt0 >> 8;

    const int w  = t >> 6;           // wave id: row group
    const int l  = t & 63;           // lane: col group
    const int w8 = w * 8;
    const int l4 = l * 4;

    float acc[8][4];
    #pragma unroll
    for (int i = 0; i < 8; ++i)
        #pragma unroll
        for (int j = 0; j < 4; ++j) acc[i][j] = 0.f;

    for (int k0 = 0; k0 < 640; k0 += KB) {
        // ---- stage As (wave 0 only; wave-uniform branch) ----
        if (t < 64) {
            const int row = t & 15;
            const int kq  = t >> 4;                     // 0..3
            float4 a4 = *(const float4*)(enc + (size_t)(bt0 + row) * 640 + k0 + kq * 4);
            As[kq * 4 + 0][row] = fmaxf(a4.x, 0.f);
            As[kq * 4 + 1][row] = fmaxf(a4.y, 0.f);
            As[kq * 4 + 2][row] = fmaxf(a4.z, 0.f);
            As[kq * 4 + 3][row] = fmaxf(a4.w, 0.f);
        }
        // ---- stage Ws: each thread 2 consecutive v-rows (stride-2 LDS stores: 2-way = free) ----
        #pragma unroll
        for (int p = 0; p < 2; ++p) {
            const int vv = t * 2 + p;
            const float* wp = W + (size_t)(v0 + vv) * 1280 + k0;   // E uses d in [0,640)
            float4 q0 = ((const float4*)wp)[0];
            float4 q1 = ((const float4*)wp)[1];
            float4 q2 = ((const float4*)wp)[2];
            float4 q3 = ((const float4*)wp)[3];
            Ws[ 0][vv] = q0.x; Ws[ 1][vv] = q0.y; Ws[ 2][vv] = q0.z; Ws[ 3][vv] = q0.w;
            Ws[ 4][vv] = q1.x; Ws[ 5][vv] = q1.y; Ws[ 6][vv] = q1.z; Ws[ 7][vv] = q1.w;
            Ws[ 8][vv] = q2.x; Ws[ 9][vv] = q2.y; Ws[10][vv] = q2.z; Ws[11][vv] = q2.w;
            Ws[12][vv] = q3.x; Ws[13][vv] = q3.y; Ws[14][vv] = q3.z; Ws[15][vv] = q3.w;
        }
        __syncthreads();

        #pragma unroll
        for (int k = 0; k < KB; ++k) {
            float4 a0 = *(const float4*)&As[k][w8];        // broadcast (1 addr/wave)
            float4 a1 = *(const float4*)&As[k][w8 + 4];    // broadcast
            float4 bv = *(const float4*)&Ws[k][l4];        // contiguous 1 KB/wave
            float ar[8] = {a0.x, a0.y, a0.z, a0.w, a1.x, a1.y, a1.z, a1.w};
            float br[4] = {bv.x, bv.y, bv.z, bv.w};
            #pragma unroll
            for (int i = 0; i < 8; ++i)
                #pragma unroll
                for (int j = 0; j < 4; ++j)
                    acc[i][j] = fmaf(ar[i], br[j], acc[i][j]);
        }
        __syncthreads();
    }

    // fold bias into the E registers (varies over v only)
    {
        float4 bb = *(const float4*)(bias + v0 + l4);
        #pragma unroll
        for (int i = 0; i < 8; ++i) {
            acc[i][0] += bb.x; acc[i][1] += bb.y; acc[i][2] += bb.z; acc[i][3] += bb.w;
        }
    }

    // ---- Phase B: stream out = E + P. 512 MB total, write-BW bound. ----
    const float* Pb = P + (size_t)b * 65536 + v0 + l4;                 // P[b*64 + u][v0 + l4]
    float* ob = out + (size_t)(bt0 + w8) * 65536 + v0 + l4;            // (bt*64+u)*1024 layout

    #pragma unroll 4
    for (int u = 0; u < 64; ++u) {
        float4 p4 = *(const float4*)(Pb + (size_t)u * 1024);
        #pragma unroll
        for (int i = 0; i < 8; ++i) {
            floatx4 o;
            o.x = acc[i][0] + p4.x;
            o.y = acc[i][1] + p4.y;
            o.z = acc[i][2] + p4.z;
            o.w = acc[i][3] + p4.w;
            __builtin_nontemporal_store(o, (floatx4*)(ob + (size_t)i * 65536 + (size_t)u * 1024));
        }
    }
}

__global__ void lengths_kernel(const int* __restrict__ sl,
                               const int* __restrict__ tl,
                               float* __restrict__ out_tail)
{
    const int i = threadIdx.x;
    if (i < 8) {
        out_tail[i]     = (float)sl[i];
        out_tail[8 + i] = (float)tl[i];
    }
}

extern "C" void kernel_launch(void* const* d_in, const int* in_sizes, int n_in,
                              void* d_out, int out_size, void* d_ws, size_t ws_size,
                              hipStream_t stream) {
    const float* enc  = (const float*)d_in[0];   // [8,256,640]
    const int*   sl   = (const int*)d_in[1];     // [8]
    const float* pred = (const float*)d_in[2];   // [8,64,640]
    const int*   tl   = (const int*)d_in[3];     // [8]
    const float* W    = (const float*)d_in[4];   // [1024,1280]
    const float* bias = (const float*)d_in[5];   // [1024]

    float* out = (float*)d_out;
    float* P   = (float*)d_ws;                   // 512*1024 f32 = 2 MB

    // P first (tiny); stream order guarantees P is complete before the fused kernel reads it.
    p_gemm_kernel<<<dim3(16, 8), 256, 0, stream>>>(pred, W, P);

    // 512 blocks = exactly 2/CU; blockIdx.x (= vtile) mod 4 is constant per XCD under
    // round-robin dispatch -> each XCD's L2 holds a single 655 KB W-slab.
    e_fused_kernel<<<dim3(4, 128), 128, 0, stream>>>(enc, W, bias, P, out);

    lengths_kernel<<<1, 64, 0, stream>>>(sl, tl, out + (size_t)131072 * 1024);
}